// Round 25
// baseline (1245.723 us; speedup 1.0000x reference)
//
#include <hip/hip_runtime.h>

typedef _Float16 half8 __attribute__((ext_vector_type(8)));
typedef _Float16 half4v __attribute__((ext_vector_type(4)));
typedef float f32x4 __attribute__((ext_vector_type(4)));

#define MFMA_F16 __builtin_amdgcn_mfma_f32_16x16x32_f16

static constexpr int BATCH  = 4096;
static constexpr int DIM    = 512;
static constexpr int CODES  = 16384;
static constexpr int NCB    = 8;
static constexpr int NCHUNK = 8;
static constexpr int CHUNK  = CODES / NCHUNK;   // 2048
static constexpr int NT     = CHUNK / 16;       // 128 tiles of 16 codes
static constexpr int HTILES = NT / 2;           // 64 tiles per block
static constexpr int BM     = 64;               // rows per block (4 bands of 16)
static constexpr int NPC    = NCHUNK * 2 * 2;   // 32 candidate slots per row (top-2)
static constexpr int UROWS  = 8;                // rows per update block
static constexpr int UBLK   = BATCH / UROWS;    // 512 update blocks
static constexpr int TILE_H = 8192;             // halfs per hi-only tile (16KB)
static constexpr int TILE_B = 16384;            // tile bytes
static constexpr float LO_SCALE = 2048.0f;
static constexpr float LO_INV   = 1.0f / 2048.0f;
static constexpr float DELTA    = 0.25f;        // screen margin (~20 sigma)

// legacy swizzle (fallback path only)
__device__ __forceinline__ int swz(int code, int kk) {
  return code * DIM + (kk ^ (((code ^ (kk >> 6)) & 7) << 3));
}

// ---------------- cvt helper: one wave converts one code of one codebook ----------
__device__ __forceinline__ void cvt_one(const float* __restrict__ cbsrc,
                                        _Float16* __restrict__ img,
                                        float* __restrict__ cnorm_k,
                                        int bid, int wave, int lane) {
  const int chunk = bid & 7;                              // XCD-pinned
  const int cidx  = (bid >> 3) * 4 + wave;
  const int ntile = cidx >> 4;
  const int code  = cidx & 15;
  const int code_g = chunk * CHUNK + cidx;

  const float* src = cbsrc + (size_t)code_g * DIM + lane * 8;
  float4 v0 = *(const float4*)src;
  float4 v1 = *(const float4*)(src + 4);
  half8 h;
  const float* f0 = (const float*)&v0;
  const float* f1 = (const float*)&v1;
  double s = 0.0;
#pragma unroll
  for (int e = 0; e < 4; ++e) {
    float x = f0[e];
    h[e] = (_Float16)x;
    s += (double)x * x;
    x = f1[e];
    h[e + 4] = (_Float16)x;
    s += (double)x * x;
  }
  const int pos = (lane >> 2) * 512 + (lane & 3) * 128 + code * 8;
  *(half8*)(img + (size_t)(chunk * NT + ntile) * TILE_H + pos) = h;

#pragma unroll
  for (int off = 32; off; off >>= 1) s += __shfl_down(s, off);
  if (lane == 0) cnorm_k[code_g] = (float)s;
}

// ---------------- fused init (resid=z, rhi split) + convert codebook 0 ----------
__global__ __launch_bounds__(256) void k_initcvt(const float* __restrict__ z,
                                                 float* __restrict__ resid,
                                                 _Float16* __restrict__ rhi,
                                                 const float* __restrict__ cb0,
                                                 _Float16* __restrict__ img0,
                                                 float* __restrict__ cnorm0) {
  if (blockIdx.x < 2048) {
    int i = blockIdx.x * 256 + threadIdx.x;      // float4 index, 524288 total
    float4 v = ((const float4*)z)[i];
    ((float4*)resid)[i] = v;
    half4v h;
    const float* vf = (const float*)&v;
#pragma unroll
    for (int j = 0; j < 4; ++j) h[j] = (_Float16)vf[j];
    *(half4v*)&rhi[(size_t)i * 4] = h;
  } else {
    cvt_one(cb0, img0, cnorm0, blockIdx.x - 2048, threadIdx.x >> 6, threadIdx.x & 63);
  }
}

// ---------------- init for fallback path (also writes rlo) ----------------
__global__ __launch_bounds__(256) void k_init(const float* __restrict__ z,
                                              float* __restrict__ resid,
                                              _Float16* __restrict__ rhi,
                                              _Float16* __restrict__ rlo) {
  int i = blockIdx.x * 256 + threadIdx.x;
  float4 v = ((const float4*)z)[i];
  ((float4*)resid)[i] = v;
  half4v h, l;
  const float* vf = (const float*)&v;
#pragma unroll
  for (int j = 0; j < 4; ++j) {
    float x = vf[j];
    _Float16 hi = (_Float16)x;
    h[j] = hi;
    l[j] = (_Float16)((x - (float)hi) * LO_SCALE);
  }
  *(half4v*)&rhi[(size_t)i * 4] = h;
  *(half4v*)&rlo[(size_t)i * 4] = l;
}

// ---------------- codebook squared norms (fallback path only) ----------------
__global__ __launch_bounds__(256) void k_cnorm(const float* __restrict__ cb,
                                               float* __restrict__ cnorm) {
  int wave = threadIdx.x >> 6, lane = threadIdx.x & 63;
  int code = blockIdx.x * 4 + wave;
  const float4* src = (const float4*)(cb + (size_t)code * DIM);
  double s = 0.0;
#pragma unroll
  for (int j = 0; j < 2; ++j) {
    float4 v = src[lane * 2 + j];
    s += (double)v.x * v.x + (double)v.y * v.y + (double)v.z * v.z + (double)v.w * v.w;
  }
#pragma unroll
  for (int off = 32; off; off >>= 1) s += __shfl_down(s, off);
  if (lane == 0) cnorm[code] = (float)s;
}

#define LEXLT(av, ai, bv, bi) ((av) < (bv) || ((av) == (bv) && (ai) < (bi)))

// ---------------- phase-1 screen: hi*hi top-2, BM=64, 1 band/wave ----------
// Each wave owns ONE band x FULL K (ah[16] = 64 VGPRs) -> total regs ~130 ->
// 3-4 waves/SIMD (vs 2 at BM=128) to hide L2 staging latency. No Xs, no
// barriers; waves free-run. setprio around MFMA clusters IS load-bearing
// (R22/R23 A/B: removing it cost ~35%).
__global__ __launch_bounds__(256, 2) void k_argmin_pc(
    const _Float16* __restrict__ rhi,
    const _Float16* __restrict__ cvt,
    const float* __restrict__ cnorm,
    float* __restrict__ partmin, int* __restrict__ partidx) {
  const int tid   = threadIdx.x;
  const int lane  = tid & 63;
  const int wave  = tid >> 6;          // owns band `wave` (0..3)
  const int chunk = blockIdx.x & 7;
  const int idx   = blockIdx.x >> 3;   // 0..127
  const int mtile = idx >> 1;          // 0..63
  const int half  = idx & 1;
  const int nt0   = half * HTILES;
  const int cbase = chunk * CHUNK;
  const char* ctile = (const char*)(cvt + (size_t)chunk * NT * TILE_H);

  const int kb = (lane >> 4) * 8;
  half8 ah[16];
  {
    const size_t rbase =
        (size_t)(mtile * BM + wave * 16 + (lane & 15)) * DIM;
#pragma unroll
    for (int t = 0; t < 16; ++t)
      ah[t] = *(const half8*)(rhi + rbase + t * 32 + kb);
  }

  const int lbase = lane * 16;
  const int rcode = lane & 15;

  float tv0[4], tv1[4];
  int   ti0[4], ti1[4];
#pragma unroll
  for (int r = 0; r < 4; ++r) {
    tv0[r] = tv1[r] = 3.4e38f;
    ti0[r] = ti1[r] = 0x7fffffff;
  }

  half8 s0[4], s1[4];

#define LOAD_Q(S, NTI, Q)                                                    \
  {                                                                          \
    const char* bp_ = ctile + (size_t)(NTI) * TILE_B + (Q) * 4096 + lbase;   \
    S[0] = *(const half8*)(bp_);                                             \
    S[1] = *(const half8*)(bp_ + 1024);                                      \
    S[2] = *(const half8*)(bp_ + 2048);                                      \
    S[3] = *(const half8*)(bp_ + 3072);                                      \
  }

#define MFMA_Q(S, TB, AI)                                                    \
  {                                                                          \
    __builtin_amdgcn_s_setprio(1);                                           \
    _Pragma("unroll")                                                        \
    for (int j_ = 0; j_ < 4; ++j_)                                           \
      acc[AI] = MFMA_F16(ah[(TB) + j_], S[j_], acc[AI], 0, 0, 0);            \
    __builtin_amdgcn_s_setprio(0);                                           \
  }

#define TOP2_INS(d, cg, R)                                                   \
  {                                                                          \
    bool b0_ = (d) < tv0[R];                                                 \
    bool b1_ = (d) < tv1[R];                                                 \
    tv1[R] = b0_ ? tv0[R] : (b1_ ? (d) : tv1[R]);                            \
    ti1[R] = b0_ ? ti0[R] : (b1_ ? (cg) : ti1[R]);                           \
    tv0[R] = b0_ ? (d) : tv0[R];                                             \
    ti0[R] = b0_ ? (cg) : ti0[R];                                            \
  }

  LOAD_Q(s0, nt0, 0);
  float cn_cur = cnorm[cbase + nt0 * 16 + rcode];

  for (int it = 0; it < HTILES; ++it) {
    const int nt = nt0 + it;
    const bool more = (it + 1 < HTILES);
    float cn_next = more ? cnorm[cbase + (nt + 1) * 16 + rcode] : 0.f;

    f32x4 acc[2];
    acc[0] = (f32x4){0.f, 0.f, 0.f, 0.f};
    acc[1] = (f32x4){0.f, 0.f, 0.f, 0.f};

    LOAD_Q(s1, nt, 1);
    MFMA_Q(s0, 0, 0);
    LOAD_Q(s0, nt, 2);
    MFMA_Q(s1, 4, 1);
    LOAD_Q(s1, nt, 3);
    MFMA_Q(s0, 8, 0);
    const int pn = more ? nt + 1 : nt;
    LOAD_Q(s0, pn, 0);
    MFMA_Q(s1, 12, 1);

    const int codeg = cbase + nt * 16 + rcode;
    f32x4 dh = acc[0] + acc[1];
#pragma unroll
    for (int r = 0; r < 4; ++r) {
      float d = cn_cur - 2.0f * dh[r];
      TOP2_INS(d, codeg, r);
    }
    cn_cur = cn_next;
  }
#undef LOAD_Q
#undef MFMA_Q
#undef TOP2_INS

#pragma unroll
  for (int s = 1; s < 16; s <<= 1) {
#pragma unroll
    for (int r = 0; r < 4; ++r) {
      float b0v = __shfl_xor(tv0[r], s), b1v = __shfl_xor(tv1[r], s);
      int   b0i = __shfl_xor(ti0[r], s), b1i = __shfl_xor(ti1[r], s);
      bool p0 = LEXLT(tv0[r], ti0[r], b0v, b0i);
      float r0v = p0 ? tv0[r] : b0v;  int r0i = p0 ? ti0[r] : b0i;
      float xv  = p0 ? b0v : tv0[r];  int xi  = p0 ? b0i : ti0[r];
      bool p1 = LEXLT(tv1[r], ti1[r], b1v, b1i);
      float yv = p1 ? tv1[r] : b1v;   int yi = p1 ? ti1[r] : b1i;
      bool p2 = LEXLT(xv, xi, yv, yi);
      float r1v = p2 ? xv : yv;       int r1i = p2 ? xi : yi;
      tv0[r] = r0v; ti0[r] = r0i;
      tv1[r] = r1v; ti1[r] = r1i;
    }
  }
  if ((lane & 15) == 0) {
    const int pslot = chunk * 2 + half;
    const int rowbase = mtile * BM + wave * 16 + (lane >> 4) * 4;
#pragma unroll
    for (int r = 0; r < 4; ++r) {
      const size_t base = (size_t)(rowbase + r) * NPC + pslot * 2;
      partmin[base + 0] = tv0[r]; partidx[base + 0] = ti0[r];
      partmin[base + 1] = tv1[r]; partidx[base + 1] = ti1[r];
    }
  }
}

// ---------------- fallback argmin (exact 3-pass, round-1 structure) ----------------
__device__ __forceinline__ void load8(const float* __restrict__ cb, int cbase, int nt,
                                      int s_code, int s_kseg, float4 v[8]) {
  const float4* src = (const float4*)(cb + (size_t)(cbase + nt * 16 + s_code) * DIM + s_kseg);
#pragma unroll
  for (int j = 0; j < 8; ++j) v[j] = src[j];
}

__device__ __forceinline__ void cvt_store(_Float16* __restrict__ BHbuf,
                                          _Float16* __restrict__ BLbuf,
                                          int code, int kseg, const float4 sv[8]) {
  const float* f = (const float*)sv;
#pragma unroll
  for (int j = 0; j < 4; ++j) {
    half8 h, l;
#pragma unroll
    for (int e = 0; e < 8; ++e) {
      float x = f[j * 8 + e];
      _Float16 hi = (_Float16)x;
      h[e] = hi;
      l[e] = (_Float16)((x - (float)hi) * LO_SCALE);
    }
    int hw = swz(code, kseg + j * 8);
    *(half8*)(BHbuf + hw) = h;
    *(half8*)(BLbuf + hw) = l;
  }
}

__global__ __launch_bounds__(256, 2) void k_argmin_fb(
    const _Float16* __restrict__ rhi, const _Float16* __restrict__ rlo,
    const float* __restrict__ cb, const float* __restrict__ cnorm,
    float* __restrict__ partmin, int* __restrict__ partidx) {
  __shared__ _Float16 BH[2][16 * DIM];
  __shared__ _Float16 BL[2][16 * DIM];
  __shared__ float CN[CHUNK];

  const int tid   = threadIdx.x;
  const int lane  = tid & 63;
  const int wave  = tid >> 6;
  const int mtile = blockIdx.x >> 3;
  const int chunk = blockIdx.x & 7;
  const int cbase = chunk * CHUNK;

  {
    const float4* s = (const float4*)(cnorm + cbase);
    float4* d = (float4*)CN;
    for (int i = tid; i < CHUNK / 4; i += 256) d[i] = s[i];
  }

  const int arow = mtile * 64 + wave * 16 + (lane & 15);
  const int kb = (lane >> 4) * 8;
  half8 ah[16], al[16];
#pragma unroll
  for (int t = 0; t < 16; ++t) {
    ah[t] = *(const half8*)(rhi + (size_t)arow * DIM + t * 32 + kb);
    al[t] = *(const half8*)(rlo + (size_t)arow * DIM + t * 32 + kb);
  }

  const int s_code = tid >> 4;
  const int s_kseg = (tid & 15) * 32;

  float rmin[4] = {3.4e38f, 3.4e38f, 3.4e38f, 3.4e38f};
  int   ridx[4] = {0, 0, 0, 0};

  {
    float4 v0[8];
    load8(cb, cbase, 0, s_code, s_kseg, v0);
    cvt_store(&BH[0][0], &BL[0][0], s_code, s_kseg, v0);
  }

  const int rcode = lane & 15;
  for (int nt = 0; nt < NT; ++nt) {
    __syncthreads();
    const int cur = nt & 1;
    const bool more = (nt + 1 < NT);
    float4 nv[8];
    if (more) load8(cb, cbase, nt + 1, s_code, s_kseg, nv);

    f32x4 acch  = {0.f, 0.f, 0.f, 0.f};
    f32x4 accl0 = {0.f, 0.f, 0.f, 0.f};
    f32x4 accl1 = {0.f, 0.f, 0.f, 0.f};
    const _Float16* bh = &BH[cur][0];
    const _Float16* bl = &BL[cur][0];
#pragma unroll
    for (int t = 0; t < 16; ++t) {
      const int hw = swz(rcode, t * 32 + kb);
      half8 fbh = *(const half8*)(bh + hw);
      half8 fbl = *(const half8*)(bl + hw);
      acch  = MFMA_F16(ah[t], fbh, acch, 0, 0, 0);
      accl0 = MFMA_F16(ah[t], fbl, accl0, 0, 0, 0);
      accl1 = MFMA_F16(al[t], fbh, accl1, 0, 0, 0);
    }
    float cn = CN[nt * 16 + rcode];
    int codeg = cbase + nt * 16 + rcode;
#pragma unroll
    for (int r = 0; r < 4; ++r) {
      float d = cn - 2.0f * (acch[r] + (accl0[r] + accl1[r]) * LO_INV);
      if (d < rmin[r]) { rmin[r] = d; ridx[r] = codeg; }
    }
    if (more) cvt_store(&BH[cur ^ 1][0], &BL[cur ^ 1][0], s_code, s_kseg, nv);
  }

#pragma unroll
  for (int s = 1; s < 16; s <<= 1) {
#pragma unroll
    for (int r = 0; r < 4; ++r) {
      float ov = __shfl_xor(rmin[r], s);
      int   oi = __shfl_xor(ridx[r], s);
      if (ov < rmin[r] || (ov == rmin[r] && oi < ridx[r])) { rmin[r] = ov; ridx[r] = oi; }
    }
  }
  if ((lane & 15) == 0) {
    int rowbase = mtile * 64 + wave * 16 + (lane >> 4) * 4;
#pragma unroll
    for (int r = 0; r < 4; ++r) {
#pragma unroll
      for (int t = 0; t < 4; ++t) {
        partmin[(size_t)(rowbase + r) * NPC + chunk * 4 + t] = rmin[r];
        partidx[(size_t)(rowbase + r) * NPC + chunk * 4 + t] = ridx[r];
      }
    }
  }
}

// ---------------- update core: UROWS rows per block ----------
// writes rlo only if rlo != nullptr (pre path passes nullptr: hi-only screen)
__device__ __forceinline__ void update_role(
    const float* __restrict__ cb, const float* __restrict__ z,
    const float* __restrict__ partmin, const int* __restrict__ partidx,
    float* __restrict__ resid, _Float16* __restrict__ rhi, _Float16* __restrict__ rlo,
    float* __restrict__ quant, float* __restrict__ out_idx,
    float* __restrict__ losspart, int step, int blk) {
  __shared__ int   s_idx[UROWS];
  __shared__ int   s_cand[UROWS][32];
  __shared__ int   s_cnt[UROWS];
  __shared__ float s_red[4];
  const int tid = threadIdx.x;
  const int row0 = blk * UROWS;

  if (tid < UROWS) {
    const int row = row0 + tid;
    float m = 3.4e38f;
    for (int c = 0; c < NPC; ++c) {
      float v = partmin[(size_t)row * NPC + c];
      if (v < m) m = v;
    }
    int cnt = 0;
    for (int c = 0; c < NPC; ++c) {
      float v = partmin[(size_t)row * NPC + c];
      if (v < m + DELTA) s_cand[tid][cnt++] = partidx[(size_t)row * NPC + c];
    }
    s_cnt[tid] = cnt;
  }
  __syncthreads();

  {
    const int wv = tid >> 6, ln = tid & 63;
    for (int rr = wv; rr < UROWS; rr += 4) {
      const int row = row0 + rr;
      const float* rrow = resid + (size_t)row * DIM + ln * 8;
      double bestd = 1.0e300;
      int    besti = 0x7fffffff;
      const int cnt = s_cnt[rr];
      for (int c = 0; c < cnt; ++c) {
        const int ci = s_cand[rr][c];
        const float* crow = cb + (size_t)ci * DIM + ln * 8;
        double s = 0.0;
#pragma unroll
        for (int e = 0; e < 8; ++e) {
          double df = (double)rrow[e] - (double)crow[e];
          s += df * df;
        }
#pragma unroll
        for (int off = 32; off; off >>= 1) s += __shfl_down(s, off);
        s = __shfl(s, 0);
        if (s < bestd || (s == bestd && ci < besti)) { bestd = s; besti = ci; }
      }
      if (ln == 0) {
        s_idx[rr] = besti;
        out_idx[(size_t)row * NCB + step] = (float)besti;
      }
    }
  }
  __syncthreads();

  float lsum = 0.f;
  const int sub = tid >> 7;
  const int e   = tid & 127;
  for (int rp = 0; rp < UROWS; rp += 2) {
    const int rl = rp + sub;
    const int row = row0 + rl;
    const int idx = s_idx[rl];
    float4 q  = ((const float4*)cb)[(size_t)idx * 128 + e];
    float4 zv = ((const float4*)z)[(size_t)row * 128 + e];
    float4 rv = ((const float4*)resid)[(size_t)row * 128 + e];
    float4 nr, qa;
    const float* qf = (const float*)&q;
    const float* zf = (const float*)&zv;
    const float* rf = (const float*)&rv;
    float* nf = (float*)&nr;
    float* af = (float*)&qa;
    if (step == 0) {
#pragma unroll
      for (int j = 0; j < 4; ++j) af[j] = qf[j];
    } else {
      float4 old = ((const float4*)quant)[(size_t)row * 128 + e];
      const float* of = (const float*)&old;
#pragma unroll
      for (int j = 0; j < 4; ++j) af[j] = of[j] + qf[j];
    }
    ((float4*)quant)[(size_t)row * 128 + e] = qa;
    half4v h, l;
#pragma unroll
    for (int j = 0; j < 4; ++j) {
      float nrj = rf[j] - qf[j];
      nf[j] = nrj;
      _Float16 hi = (_Float16)nrj;
      h[j] = hi;
      l[j] = (_Float16)((nrj - (float)hi) * LO_SCALE);
      float dq = qf[j] - zf[j];
      lsum += dq * dq;
    }
    ((float4*)resid)[(size_t)row * 128 + e] = nr;
    *(half4v*)&rhi[(size_t)row * DIM + e * 4] = h;
    if (rlo) *(half4v*)&rlo[(size_t)row * DIM + e * 4] = l;
  }
#pragma unroll
  for (int off = 32; off; off >>= 1) lsum += __shfl_down(lsum, off);
  if ((tid & 63) == 0) s_red[tid >> 6] = lsum;
  __syncthreads();
  if (tid == 0) losspart[blk] = s_red[0] + s_red[1] + s_red[2] + s_red[3];
}

// ---------------- fused: update step k (blocks 0..UBLK-1) + convert codebook k+1 ----
__global__ __launch_bounds__(256) void k_upcvt(
    const float* __restrict__ cbk, const float* __restrict__ z,
    const float* __restrict__ partmin, const int* __restrict__ partidx,
    float* __restrict__ resid, _Float16* __restrict__ rhi,
    float* __restrict__ quant, float* __restrict__ out_idx,
    float* __restrict__ losspart, int step,
    const float* __restrict__ cbn, _Float16* __restrict__ imgn,
    float* __restrict__ cnormn) {
  if (blockIdx.x < UBLK) {
    update_role(cbk, z, partmin, partidx, resid, rhi, nullptr,
                quant, out_idx, losspart, step, blockIdx.x);
  } else {
    cvt_one(cbn, imgn, cnormn, blockIdx.x - UBLK, threadIdx.x >> 6, threadIdx.x & 63);
  }
}

// ---------------- plain update (last step + fallback path) ----------------
__global__ __launch_bounds__(256) void k_update(
    const float* __restrict__ cb, const float* __restrict__ z,
    const float* __restrict__ partmin, const int* __restrict__ partidx,
    float* __restrict__ resid, _Float16* __restrict__ rhi, _Float16* __restrict__ rlo,
    float* __restrict__ quant, float* __restrict__ out_idx,
    float* __restrict__ losspart, int step) {
  update_role(cb, z, partmin, partidx, resid, rhi, rlo,
              quant, out_idx, losspart, step, blockIdx.x);
}

// ---------------- final loss: 256-thread f64 reduction ----------------
__global__ __launch_bounds__(256) void k_loss(const float* __restrict__ losspart,
                                              float* __restrict__ out_loss) {
  __shared__ double red[4];
  const int tid = threadIdx.x;
  double s = 0.0;
  for (int i = tid; i < NCB * UBLK; i += 256) s += (double)losspart[i];
#pragma unroll
  for (int off = 32; off; off >>= 1) s += __shfl_down(s, off);
  if ((tid & 63) == 0) red[tid >> 6] = s;
  __syncthreads();
  if (tid == 0)
    out_loss[0] = (float)((red[0] + red[1] + red[2] + red[3]) *
                          (1.25 / (double)((size_t)BATCH * DIM)));
}

extern "C" void kernel_launch(void* const* d_in, const int* in_sizes, int n_in,
                              void* d_out, int out_size, void* d_ws, size_t ws_size,
                              hipStream_t stream) {
  const float* z  = (const float*)d_in[0];
  const float* cb = (const float*)d_in[1];
  float* out = (float*)d_out;
  float* quant    = out;
  float* out_loss = out + (size_t)BATCH * DIM;
  float* out_idx  = out + (size_t)BATCH * DIM + 1;

  char* ws = (char*)d_ws;
  float*    resid    = (float*)ws;                                  // 8 MB
  _Float16* rhi      = (_Float16*)(ws + ((size_t)8  << 20));        // 4 MB
  _Float16* rlo      = (_Float16*)(ws + ((size_t)12 << 20));        // 4 MB (fallback only)
  float*    cnorm    = (float*)(ws + ((size_t)16 << 20));           // 512 KB (all codebooks)
  float*    partmin  = (float*)(ws + ((size_t)17 << 20));           // 512 KB
  int*      partidx  = (int*)  (ws + ((size_t)18 << 20));           // 512 KB
  float*    losspart = (float*)(ws + ((size_t)19 << 20));           // 16 KB
  _Float16* cvtbuf0  = (_Float16*)(ws + ((size_t)20 << 20));        // 16 MB
  _Float16* cvtbuf1  = (_Float16*)(ws + ((size_t)36 << 20));        // 16 MB

  const size_t REQ = ((size_t)36 << 20) + ((size_t)16 << 20);
  const bool pre = (ws_size >= REQ);

  if (pre) {
    // fused init + convert codebook 0 into cvtbuf0
    k_initcvt<<<dim3(2048 + 4096), dim3(256), 0, stream>>>(
        z, resid, rhi, cb, cvtbuf0, cnorm);

    for (int k = 0; k < NCB; ++k) {
      const float* cbk = cb + (size_t)k * CODES * DIM;
      _Float16* imgk = (k & 1) ? cvtbuf1 : cvtbuf0;
      k_argmin_pc<<<dim3((BATCH / BM) * NCHUNK * 2), dim3(256), 0, stream>>>(
          rhi, imgk, cnorm + (size_t)k * CODES, partmin, partidx);
      if (k + 1 < NCB) {
        const float* cbn = cb + (size_t)(k + 1) * CODES * DIM;
        _Float16* imgn = ((k + 1) & 1) ? cvtbuf1 : cvtbuf0;
        // fused: update step k + convert codebook k+1
        k_upcvt<<<dim3(UBLK + 4096), dim3(256), 0, stream>>>(
            cbk, z, partmin, partidx, resid, rhi,
            quant, out_idx, losspart + k * UBLK, k,
            cbn, imgn, cnorm + (size_t)(k + 1) * CODES);
      } else {
        k_update<<<dim3(UBLK), dim3(256), 0, stream>>>(
            cbk, z, partmin, partidx, resid, rhi, nullptr,
            quant, out_idx, losspart + k * UBLK, k);
      }
    }
  } else {
    k_init<<<dim3((BATCH * DIM / 4) / 256), dim3(256), 0, stream>>>(z, resid, rhi, rlo);
    k_cnorm<<<dim3(NCB * CODES / 4), dim3(256), 0, stream>>>(cb, cnorm);
    for (int k = 0; k < NCB; ++k) {
      const float* cbk = cb + (size_t)k * CODES * DIM;
      k_argmin_fb<<<dim3((BATCH / 64) * NCHUNK), dim3(256), 0, stream>>>(
          rhi, rlo, cbk, cnorm + (size_t)k * CODES, partmin, partidx);
      k_update<<<dim3(UBLK), dim3(256), 0, stream>>>(
          cbk, z, partmin, partidx, resid, rhi, rlo,
          quant, out_idx, losspart + k * UBLK, k);
    }
  }
  k_loss<<<dim3(1), dim3(256), 0, stream>>>(losspart, out_loss);
}

// Round 26
// 859.427 us; speedup vs baseline: 1.4495x; 1.4495x over previous
//
#include <hip/hip_runtime.h>

typedef _Float16 half8 __attribute__((ext_vector_type(8)));
typedef _Float16 half4v __attribute__((ext_vector_type(4)));
typedef float f32x4 __attribute__((ext_vector_type(4)));

#define MFMA_F16 __builtin_amdgcn_mfma_f32_16x16x32_f16

static constexpr int BATCH  = 4096;
static constexpr int DIM    = 512;
static constexpr int CODES  = 16384;
static constexpr int NCB    = 8;
static constexpr int NCHUNK = 8;
static constexpr int CHUNK  = CODES / NCHUNK;   // 2048
static constexpr int NT     = CHUNK / 16;       // 128 tiles of 16 codes
static constexpr int HTILES = NT / 2;           // 64 tiles per block
static constexpr int BM     = 128;              // rows per block (8 bands of 16)
static constexpr int NPC    = NCHUNK * 2 * 2;   // 32 candidate slots per row (top-2)
static constexpr int UROWS  = 8;                // rows per update block
static constexpr int UBLK   = BATCH / UROWS;    // 512 update blocks
static constexpr int TILE_H = 8192;             // halfs per hi-only tile (16KB)
static constexpr int TILE_B = 16384;            // tile bytes
static constexpr float LO_SCALE = 2048.0f;
static constexpr float LO_INV   = 1.0f / 2048.0f;
static constexpr float DELTA    = 0.25f;        // screen margin (~20 sigma)

// legacy swizzle (fallback path only)
__device__ __forceinline__ int swz(int code, int kk) {
  return code * DIM + (kk ^ (((code ^ (kk >> 6)) & 7) << 3));
}

// ---------------- cvt helper: one wave converts one code of one codebook ----------
__device__ __forceinline__ void cvt_one(const float* __restrict__ cbsrc,
                                        _Float16* __restrict__ img,
                                        float* __restrict__ cnorm_k,
                                        int bid, int wave, int lane) {
  const int chunk = bid & 7;                              // XCD-pinned
  const int cidx  = (bid >> 3) * 4 + wave;
  const int ntile = cidx >> 4;
  const int code  = cidx & 15;
  const int code_g = chunk * CHUNK + cidx;

  const float* src = cbsrc + (size_t)code_g * DIM + lane * 8;
  float4 v0 = *(const float4*)src;
  float4 v1 = *(const float4*)(src + 4);
  half8 h;
  const float* f0 = (const float*)&v0;
  const float* f1 = (const float*)&v1;
  double s = 0.0;
#pragma unroll
  for (int e = 0; e < 4; ++e) {
    float x = f0[e];
    h[e] = (_Float16)x;
    s += (double)x * x;
    x = f1[e];
    h[e + 4] = (_Float16)x;
    s += (double)x * x;
  }
  const int pos = (lane >> 2) * 512 + (lane & 3) * 128 + code * 8;
  *(half8*)(img + (size_t)(chunk * NT + ntile) * TILE_H + pos) = h;

#pragma unroll
  for (int off = 32; off; off >>= 1) s += __shfl_down(s, off);
  if (lane == 0) cnorm_k[code_g] = (float)s;
}

// ---------------- fused init (resid=z, rhi split) + convert codebook 0 ----------
__global__ __launch_bounds__(256) void k_initcvt(const float* __restrict__ z,
                                                 float* __restrict__ resid,
                                                 _Float16* __restrict__ rhi,
                                                 const float* __restrict__ cb0,
                                                 _Float16* __restrict__ img0,
                                                 float* __restrict__ cnorm0) {
  if (blockIdx.x < 2048) {
    int i = blockIdx.x * 256 + threadIdx.x;      // float4 index, 524288 total
    float4 v = ((const float4*)z)[i];
    ((float4*)resid)[i] = v;
    half4v h;
    const float* vf = (const float*)&v;
#pragma unroll
    for (int j = 0; j < 4; ++j) h[j] = (_Float16)vf[j];
    *(half4v*)&rhi[(size_t)i * 4] = h;
  } else {
    cvt_one(cb0, img0, cnorm0, blockIdx.x - 2048, threadIdx.x >> 6, threadIdx.x & 63);
  }
}

// ---------------- init for fallback path (also writes rlo) ----------------
__global__ __launch_bounds__(256) void k_init(const float* __restrict__ z,
                                              float* __restrict__ resid,
                                              _Float16* __restrict__ rhi,
                                              _Float16* __restrict__ rlo) {
  int i = blockIdx.x * 256 + threadIdx.x;
  float4 v = ((const float4*)z)[i];
  ((float4*)resid)[i] = v;
  half4v h, l;
  const float* vf = (const float*)&v;
#pragma unroll
  for (int j = 0; j < 4; ++j) {
    float x = vf[j];
    _Float16 hi = (_Float16)x;
    h[j] = hi;
    l[j] = (_Float16)((x - (float)hi) * LO_SCALE);
  }
  *(half4v*)&rhi[(size_t)i * 4] = h;
  *(half4v*)&rlo[(size_t)i * 4] = l;
}

// ---------------- codebook squared norms (fallback path only) ----------------
__global__ __launch_bounds__(256) void k_cnorm(const float* __restrict__ cb,
                                               float* __restrict__ cnorm) {
  int wave = threadIdx.x >> 6, lane = threadIdx.x & 63;
  int code = blockIdx.x * 4 + wave;
  const float4* src = (const float4*)(cb + (size_t)code * DIM);
  double s = 0.0;
#pragma unroll
  for (int j = 0; j < 2; ++j) {
    float4 v = src[lane * 2 + j];
    s += (double)v.x * v.x + (double)v.y * v.y + (double)v.z * v.z + (double)v.w * v.w;
  }
#pragma unroll
  for (int off = 32; off; off >>= 1) s += __shfl_down(s, off);
  if (lane == 0) cnorm[code] = (float)s;
}

#define LEXLT(av, ai, bv, bi) ((av) < (bv) || ((av) == (bv) && (ai) < (bi)))

// ---------------- phase-1 screen: hi*hi top-2, BM=128, NO exchange ----------
// Each wave owns 2 bands x FULL K (ah[2][16]); complete dot products -> no Xs,
// no barriers; the 8 resident waves free-run. setprio around MFMA clusters IS
// load-bearing (R22/R23 A/B: removing it cost ~35%). BM=64 is load-issue-bound
// (R25: 2x staging traffic, +55% regression). launch_bounds stays (256,2).
__global__ __launch_bounds__(256, 2) void k_argmin_pc(
    const _Float16* __restrict__ rhi,
    const _Float16* __restrict__ cvt,
    const float* __restrict__ cnorm,
    float* __restrict__ partmin, int* __restrict__ partidx) {
  const int tid   = threadIdx.x;
  const int lane  = tid & 63;
  const int wave  = tid >> 6;          // owns bands {2*wave, 2*wave+1}
  const int chunk = blockIdx.x & 7;
  const int idx   = blockIdx.x >> 3;   // 0..63
  const int mtile = idx >> 1;          // 0..31
  const int half  = idx & 1;
  const int nt0   = half * HTILES;
  const int cbase = chunk * CHUNK;
  const char* ctile = (const char*)(cvt + (size_t)chunk * NT * TILE_H);

  const int kb = (lane >> 4) * 8;
  half8 ah[2][16];
#pragma unroll
  for (int j = 0; j < 2; ++j) {
    const size_t rbase =
        (size_t)(mtile * BM + (2 * wave + j) * 16 + (lane & 15)) * DIM;
#pragma unroll
    for (int t = 0; t < 16; ++t)
      ah[j][t] = *(const half8*)(rhi + rbase + t * 32 + kb);
  }

  const int lbase = lane * 16;
  const int rcode = lane & 15;

  float tv0[2][4], tv1[2][4];
  int   ti0[2][4], ti1[2][4];
#pragma unroll
  for (int j = 0; j < 2; ++j)
#pragma unroll
    for (int r = 0; r < 4; ++r) {
      tv0[j][r] = tv1[j][r] = 3.4e38f;
      ti0[j][r] = ti1[j][r] = 0x7fffffff;
    }

  half8 s0[4], s1[4];

#define LOAD_Q(S, NTI, Q)                                                    \
  {                                                                          \
    const char* bp_ = ctile + (size_t)(NTI) * TILE_B + (Q) * 4096 + lbase;   \
    S[0] = *(const half8*)(bp_);                                             \
    S[1] = *(const half8*)(bp_ + 1024);                                      \
    S[2] = *(const half8*)(bp_ + 2048);                                      \
    S[3] = *(const half8*)(bp_ + 3072);                                      \
  }

#define MFMA_Q(S, TB, AI)                                                    \
  {                                                                          \
    __builtin_amdgcn_s_setprio(1);                                           \
    _Pragma("unroll")                                                        \
    for (int j_ = 0; j_ < 4; ++j_) {                                         \
      _Pragma("unroll")                                                      \
      for (int b_ = 0; b_ < 2; ++b_)                                         \
        acc[b_][AI] = MFMA_F16(ah[b_][(TB) + j_], S[j_], acc[b_][AI], 0, 0, 0); \
    }                                                                        \
    __builtin_amdgcn_s_setprio(0);                                           \
  }

#define TOP2_INS(d, cg, J, R)                                                \
  {                                                                          \
    bool b0_ = (d) < tv0[J][R];                                              \
    bool b1_ = (d) < tv1[J][R];                                              \
    tv1[J][R] = b0_ ? tv0[J][R] : (b1_ ? (d) : tv1[J][R]);                   \
    ti1[J][R] = b0_ ? ti0[J][R] : (b1_ ? (cg) : ti1[J][R]);                  \
    tv0[J][R] = b0_ ? (d) : tv0[J][R];                                       \
    ti0[J][R] = b0_ ? (cg) : ti0[J][R];                                      \
  }

  LOAD_Q(s0, nt0, 0);
  float cn_cur = cnorm[cbase + nt0 * 16 + rcode];

  for (int it = 0; it < HTILES; ++it) {
    const int nt = nt0 + it;
    const bool more = (it + 1 < HTILES);
    float cn_next = more ? cnorm[cbase + (nt + 1) * 16 + rcode] : 0.f;

    f32x4 acc[2][2];
#pragma unroll
    for (int b = 0; b < 2; ++b) {
      acc[b][0] = (f32x4){0.f, 0.f, 0.f, 0.f};
      acc[b][1] = (f32x4){0.f, 0.f, 0.f, 0.f};
    }

    LOAD_Q(s1, nt, 1);
    MFMA_Q(s0, 0, 0);
    LOAD_Q(s0, nt, 2);
    MFMA_Q(s1, 4, 1);
    LOAD_Q(s1, nt, 3);
    MFMA_Q(s0, 8, 0);
    const int pn = more ? nt + 1 : nt;
    LOAD_Q(s0, pn, 0);
    MFMA_Q(s1, 12, 1);

    const int codeg = cbase + nt * 16 + rcode;
#pragma unroll
    for (int j = 0; j < 2; ++j) {
      f32x4 dh = acc[j][0] + acc[j][1];
#pragma unroll
      for (int r = 0; r < 4; ++r) {
        float d = cn_cur - 2.0f * dh[r];
        TOP2_INS(d, codeg, j, r);
      }
    }
    cn_cur = cn_next;
  }
#undef LOAD_Q
#undef MFMA_Q
#undef TOP2_INS

#pragma unroll
  for (int s = 1; s < 16; s <<= 1) {
#pragma unroll
    for (int j = 0; j < 2; ++j) {
#pragma unroll
      for (int r = 0; r < 4; ++r) {
        float b0v = __shfl_xor(tv0[j][r], s), b1v = __shfl_xor(tv1[j][r], s);
        int   b0i = __shfl_xor(ti0[j][r], s), b1i = __shfl_xor(ti1[j][r], s);
        bool p0 = LEXLT(tv0[j][r], ti0[j][r], b0v, b0i);
        float r0v = p0 ? tv0[j][r] : b0v;  int r0i = p0 ? ti0[j][r] : b0i;
        float xv  = p0 ? b0v : tv0[j][r];  int xi  = p0 ? b0i : ti0[j][r];
        bool p1 = LEXLT(tv1[j][r], ti1[j][r], b1v, b1i);
        float yv = p1 ? tv1[j][r] : b1v;   int yi = p1 ? ti1[j][r] : b1i;
        bool p2 = LEXLT(xv, xi, yv, yi);
        float r1v = p2 ? xv : yv;          int r1i = p2 ? xi : yi;
        tv0[j][r] = r0v; ti0[j][r] = r0i;
        tv1[j][r] = r1v; ti1[j][r] = r1i;
      }
    }
  }
  if ((lane & 15) == 0) {
    const int pslot = chunk * 2 + half;
#pragma unroll
    for (int j = 0; j < 2; ++j) {
      const int rowbase = mtile * BM + (2 * wave + j) * 16 + (lane >> 4) * 4;
#pragma unroll
      for (int r = 0; r < 4; ++r) {
        const size_t base = (size_t)(rowbase + r) * NPC + pslot * 2;
        partmin[base + 0] = tv0[j][r]; partidx[base + 0] = ti0[j][r];
        partmin[base + 1] = tv1[j][r]; partidx[base + 1] = ti1[j][r];
      }
    }
  }
}

// ---------------- fallback argmin (exact 3-pass, round-1 structure) ----------------
__device__ __forceinline__ void load8(const float* __restrict__ cb, int cbase, int nt,
                                      int s_code, int s_kseg, float4 v[8]) {
  const float4* src = (const float4*)(cb + (size_t)(cbase + nt * 16 + s_code) * DIM + s_kseg);
#pragma unroll
  for (int j = 0; j < 8; ++j) v[j] = src[j];
}

__device__ __forceinline__ void cvt_store(_Float16* __restrict__ BHbuf,
                                          _Float16* __restrict__ BLbuf,
                                          int code, int kseg, const float4 sv[8]) {
  const float* f = (const float*)sv;
#pragma unroll
  for (int j = 0; j < 4; ++j) {
    half8 h, l;
#pragma unroll
    for (int e = 0; e < 8; ++e) {
      float x = f[j * 8 + e];
      _Float16 hi = (_Float16)x;
      h[e] = hi;
      l[e] = (_Float16)((x - (float)hi) * LO_SCALE);
    }
    int hw = swz(code, kseg + j * 8);
    *(half8*)(BHbuf + hw) = h;
    *(half8*)(BLbuf + hw) = l;
  }
}

__global__ __launch_bounds__(256, 2) void k_argmin_fb(
    const _Float16* __restrict__ rhi, const _Float16* __restrict__ rlo,
    const float* __restrict__ cb, const float* __restrict__ cnorm,
    float* __restrict__ partmin, int* __restrict__ partidx) {
  __shared__ _Float16 BH[2][16 * DIM];
  __shared__ _Float16 BL[2][16 * DIM];
  __shared__ float CN[CHUNK];

  const int tid   = threadIdx.x;
  const int lane  = tid & 63;
  const int wave  = tid >> 6;
  const int mtile = blockIdx.x >> 3;
  const int chunk = blockIdx.x & 7;
  const int cbase = chunk * CHUNK;

  {
    const float4* s = (const float4*)(cnorm + cbase);
    float4* d = (float4*)CN;
    for (int i = tid; i < CHUNK / 4; i += 256) d[i] = s[i];
  }

  const int arow = mtile * 64 + wave * 16 + (lane & 15);
  const int kb = (lane >> 4) * 8;
  half8 ah[16], al[16];
#pragma unroll
  for (int t = 0; t < 16; ++t) {
    ah[t] = *(const half8*)(rhi + (size_t)arow * DIM + t * 32 + kb);
    al[t] = *(const half8*)(rlo + (size_t)arow * DIM + t * 32 + kb);
  }

  const int s_code = tid >> 4;
  const int s_kseg = (tid & 15) * 32;

  float rmin[4] = {3.4e38f, 3.4e38f, 3.4e38f, 3.4e38f};
  int   ridx[4] = {0, 0, 0, 0};

  {
    float4 v0[8];
    load8(cb, cbase, 0, s_code, s_kseg, v0);
    cvt_store(&BH[0][0], &BL[0][0], s_code, s_kseg, v0);
  }

  const int rcode = lane & 15;
  for (int nt = 0; nt < NT; ++nt) {
    __syncthreads();
    const int cur = nt & 1;
    const bool more = (nt + 1 < NT);
    float4 nv[8];
    if (more) load8(cb, cbase, nt + 1, s_code, s_kseg, nv);

    f32x4 acch  = {0.f, 0.f, 0.f, 0.f};
    f32x4 accl0 = {0.f, 0.f, 0.f, 0.f};
    f32x4 accl1 = {0.f, 0.f, 0.f, 0.f};
    const _Float16* bh = &BH[cur][0];
    const _Float16* bl = &BL[cur][0];
#pragma unroll
    for (int t = 0; t < 16; ++t) {
      const int hw = swz(rcode, t * 32 + kb);
      half8 fbh = *(const half8*)(bh + hw);
      half8 fbl = *(const half8*)(bl + hw);
      acch  = MFMA_F16(ah[t], fbh, acch, 0, 0, 0);
      accl0 = MFMA_F16(ah[t], fbl, accl0, 0, 0, 0);
      accl1 = MFMA_F16(al[t], fbh, accl1, 0, 0, 0);
    }
    float cn = CN[nt * 16 + rcode];
    int codeg = cbase + nt * 16 + rcode;
#pragma unroll
    for (int r = 0; r < 4; ++r) {
      float d = cn - 2.0f * (acch[r] + (accl0[r] + accl1[r]) * LO_INV);
      if (d < rmin[r]) { rmin[r] = d; ridx[r] = codeg; }
    }
    if (more) cvt_store(&BH[cur ^ 1][0], &BL[cur ^ 1][0], s_code, s_kseg, nv);
  }

#pragma unroll
  for (int s = 1; s < 16; s <<= 1) {
#pragma unroll
    for (int r = 0; r < 4; ++r) {
      float ov = __shfl_xor(rmin[r], s);
      int   oi = __shfl_xor(ridx[r], s);
      if (ov < rmin[r] || (ov == rmin[r] && oi < ridx[r])) { rmin[r] = ov; ridx[r] = oi; }
    }
  }
  if ((lane & 15) == 0) {
    int rowbase = mtile * 64 + wave * 16 + (lane >> 4) * 4;
#pragma unroll
    for (int r = 0; r < 4; ++r) {
#pragma unroll
      for (int t = 0; t < 4; ++t) {
        partmin[(size_t)(rowbase + r) * NPC + chunk * 4 + t] = rmin[r];
        partidx[(size_t)(rowbase + r) * NPC + chunk * 4 + t] = ridx[r];
      }
    }
  }
}

// ---------------- update core: UROWS rows per block ----------
// writes rlo only if rlo != nullptr (pre path passes nullptr: hi-only screen)
__device__ __forceinline__ void update_role(
    const float* __restrict__ cb, const float* __restrict__ z,
    const float* __restrict__ partmin, const int* __restrict__ partidx,
    float* __restrict__ resid, _Float16* __restrict__ rhi, _Float16* __restrict__ rlo,
    float* __restrict__ quant, float* __restrict__ out_idx,
    float* __restrict__ losspart, int step, int blk) {
  __shared__ int   s_idx[UROWS];
  __shared__ int   s_cand[UROWS][32];
  __shared__ int   s_cnt[UROWS];
  __shared__ float s_red[4];
  const int tid = threadIdx.x;
  const int row0 = blk * UROWS;

  if (tid < UROWS) {
    const int row = row0 + tid;
    float m = 3.4e38f;
    for (int c = 0; c < NPC; ++c) {
      float v = partmin[(size_t)row * NPC + c];
      if (v < m) m = v;
    }
    int cnt = 0;
    for (int c = 0; c < NPC; ++c) {
      float v = partmin[(size_t)row * NPC + c];
      if (v < m + DELTA) s_cand[tid][cnt++] = partidx[(size_t)row * NPC + c];
    }
    s_cnt[tid] = cnt;
  }
  __syncthreads();

  {
    const int wv = tid >> 6, ln = tid & 63;
    for (int rr = wv; rr < UROWS; rr += 4) {
      const int row = row0 + rr;
      const float* rrow = resid + (size_t)row * DIM + ln * 8;
      double bestd = 1.0e300;
      int    besti = 0x7fffffff;
      const int cnt = s_cnt[rr];
      for (int c = 0; c < cnt; ++c) {
        const int ci = s_cand[rr][c];
        const float* crow = cb + (size_t)ci * DIM + ln * 8;
        double s = 0.0;
#pragma unroll
        for (int e = 0; e < 8; ++e) {
          double df = (double)rrow[e] - (double)crow[e];
          s += df * df;
        }
#pragma unroll
        for (int off = 32; off; off >>= 1) s += __shfl_down(s, off);
        s = __shfl(s, 0);
        if (s < bestd || (s == bestd && ci < besti)) { bestd = s; besti = ci; }
      }
      if (ln == 0) {
        s_idx[rr] = besti;
        out_idx[(size_t)row * NCB + step] = (float)besti;
      }
    }
  }
  __syncthreads();

  float lsum = 0.f;
  const int sub = tid >> 7;
  const int e   = tid & 127;
  for (int rp = 0; rp < UROWS; rp += 2) {
    const int rl = rp + sub;
    const int row = row0 + rl;
    const int idx = s_idx[rl];
    float4 q  = ((const float4*)cb)[(size_t)idx * 128 + e];
    float4 zv = ((const float4*)z)[(size_t)row * 128 + e];
    float4 rv = ((const float4*)resid)[(size_t)row * 128 + e];
    float4 nr, qa;
    const float* qf = (const float*)&q;
    const float* zf = (const float*)&zv;
    const float* rf = (const float*)&rv;
    float* nf = (float*)&nr;
    float* af = (float*)&qa;
    if (step == 0) {
#pragma unroll
      for (int j = 0; j < 4; ++j) af[j] = qf[j];
    } else {
      float4 old = ((const float4*)quant)[(size_t)row * 128 + e];
      const float* of = (const float*)&old;
#pragma unroll
      for (int j = 0; j < 4; ++j) af[j] = of[j] + qf[j];
    }
    ((float4*)quant)[(size_t)row * 128 + e] = qa;
    half4v h, l;
#pragma unroll
    for (int j = 0; j < 4; ++j) {
      float nrj = rf[j] - qf[j];
      nf[j] = nrj;
      _Float16 hi = (_Float16)nrj;
      h[j] = hi;
      l[j] = (_Float16)((nrj - (float)hi) * LO_SCALE);
      float dq = qf[j] - zf[j];
      lsum += dq * dq;
    }
    ((float4*)resid)[(size_t)row * 128 + e] = nr;
    *(half4v*)&rhi[(size_t)row * DIM + e * 4] = h;
    if (rlo) *(half4v*)&rlo[(size_t)row * DIM + e * 4] = l;
  }
#pragma unroll
  for (int off = 32; off; off >>= 1) lsum += __shfl_down(lsum, off);
  if ((tid & 63) == 0) s_red[tid >> 6] = lsum;
  __syncthreads();
  if (tid == 0) losspart[blk] = s_red[0] + s_red[1] + s_red[2] + s_red[3];
}

// ---------------- fused: update step k (blocks 0..UBLK-1) + convert codebook k+1 ----
__global__ __launch_bounds__(256) void k_upcvt(
    const float* __restrict__ cbk, const float* __restrict__ z,
    const float* __restrict__ partmin, const int* __restrict__ partidx,
    float* __restrict__ resid, _Float16* __restrict__ rhi,
    float* __restrict__ quant, float* __restrict__ out_idx,
    float* __restrict__ losspart, int step,
    const float* __restrict__ cbn, _Float16* __restrict__ imgn,
    float* __restrict__ cnormn) {
  if (blockIdx.x < UBLK) {
    update_role(cbk, z, partmin, partidx, resid, rhi, nullptr,
                quant, out_idx, losspart, step, blockIdx.x);
  } else {
    cvt_one(cbn, imgn, cnormn, blockIdx.x - UBLK, threadIdx.x >> 6, threadIdx.x & 63);
  }
}

// ---------------- plain update (last step + fallback path) ----------------
__global__ __launch_bounds__(256) void k_update(
    const float* __restrict__ cb, const float* __restrict__ z,
    const float* __restrict__ partmin, const int* __restrict__ partidx,
    float* __restrict__ resid, _Float16* __restrict__ rhi, _Float16* __restrict__ rlo,
    float* __restrict__ quant, float* __restrict__ out_idx,
    float* __restrict__ losspart, int step) {
  update_role(cb, z, partmin, partidx, resid, rhi, rlo,
              quant, out_idx, losspart, step, blockIdx.x);
}

// ---------------- final loss: 256-thread f64 reduction ----------------
__global__ __launch_bounds__(256) void k_loss(const float* __restrict__ losspart,
                                              float* __restrict__ out_loss) {
  __shared__ double red[4];
  const int tid = threadIdx.x;
  double s = 0.0;
  for (int i = tid; i < NCB * UBLK; i += 256) s += (double)losspart[i];
#pragma unroll
  for (int off = 32; off; off >>= 1) s += __shfl_down(s, off);
  if ((tid & 63) == 0) red[tid >> 6] = s;
  __syncthreads();
  if (tid == 0)
    out_loss[0] = (float)((red[0] + red[1] + red[2] + red[3]) *
                          (1.25 / (double)((size_t)BATCH * DIM)));
}

extern "C" void kernel_launch(void* const* d_in, const int* in_sizes, int n_in,
                              void* d_out, int out_size, void* d_ws, size_t ws_size,
                              hipStream_t stream) {
  const float* z  = (const float*)d_in[0];
  const float* cb = (const float*)d_in[1];
  float* out = (float*)d_out;
  float* quant    = out;
  float* out_loss = out + (size_t)BATCH * DIM;
  float* out_idx  = out + (size_t)BATCH * DIM + 1;

  char* ws = (char*)d_ws;
  float*    resid    = (float*)ws;                                  // 8 MB
  _Float16* rhi      = (_Float16*)(ws + ((size_t)8  << 20));        // 4 MB
  _Float16* rlo      = (_Float16*)(ws + ((size_t)12 << 20));        // 4 MB (fallback only)
  float*    cnorm    = (float*)(ws + ((size_t)16 << 20));           // 512 KB (all codebooks)
  float*    partmin  = (float*)(ws + ((size_t)17 << 20));           // 512 KB
  int*      partidx  = (int*)  (ws + ((size_t)18 << 20));           // 512 KB
  float*    losspart = (float*)(ws + ((size_t)19 << 20));           // 16 KB
  _Float16* cvtbuf0  = (_Float16*)(ws + ((size_t)20 << 20));        // 16 MB
  _Float16* cvtbuf1  = (_Float16*)(ws + ((size_t)36 << 20));        // 16 MB

  const size_t REQ = ((size_t)36 << 20) + ((size_t)16 << 20);
  const bool pre = (ws_size >= REQ);

  if (pre) {
    // fused init + convert codebook 0 into cvtbuf0
    k_initcvt<<<dim3(2048 + 4096), dim3(256), 0, stream>>>(
        z, resid, rhi, cb, cvtbuf0, cnorm);

    for (int k = 0; k < NCB; ++k) {
      const float* cbk = cb + (size_t)k * CODES * DIM;
      _Float16* imgk = (k & 1) ? cvtbuf1 : cvtbuf0;
      k_argmin_pc<<<dim3((BATCH / BM) * NCHUNK * 2), dim3(256), 0, stream>>>(
          rhi, imgk, cnorm + (size_t)k * CODES, partmin, partidx);
      if (k + 1 < NCB) {
        const float* cbn = cb + (size_t)(k + 1) * CODES * DIM;
        _Float16* imgn = ((k + 1) & 1) ? cvtbuf1 : cvtbuf0;
        // fused: update step k + convert codebook k+1
        k_upcvt<<<dim3(UBLK + 4096), dim3(256), 0, stream>>>(
            cbk, z, partmin, partidx, resid, rhi,
            quant, out_idx, losspart + k * UBLK, k,
            cbn, imgn, cnorm + (size_t)(k + 1) * CODES);
      } else {
        k_update<<<dim3(UBLK), dim3(256), 0, stream>>>(
            cbk, z, partmin, partidx, resid, rhi, nullptr,
            quant, out_idx, losspart + k * UBLK, k);
      }
    }
  } else {
    k_init<<<dim3((BATCH * DIM / 4) / 256), dim3(256), 0, stream>>>(z, resid, rhi, rlo);
    k_cnorm<<<dim3(NCB * CODES / 4), dim3(256), 0, stream>>>(cb, cnorm);
    for (int k = 0; k < NCB; ++k) {
      const float* cbk = cb + (size_t)k * CODES * DIM;
      k_argmin_fb<<<dim3((BATCH / 64) * NCHUNK), dim3(256), 0, stream>>>(
          rhi, rlo, cbk, cnorm + (size_t)k * CODES, partmin, partidx);
      k_update<<<dim3(UBLK), dim3(256), 0, stream>>>(
          cbk, z, partmin, partidx, resid, rhi, rlo,
          quant, out_idx, losspart + k * UBLK, k);
    }
  }
  k_loss<<<dim3(1), dim3(256), 0, stream>>>(losspart, out_loss);
}